// Round 1
// baseline (2347.554 us; speedup 1.0000x reference)
//
#include <hip/hip_runtime.h>

#define R 8
#define BLK 256
#define TSTEPS 255
#define GATE 256
#define NDI 16
#define SDI 8
#define HDI 64
#define INDIM 24
#define KCAT 88

__device__ __forceinline__ float frcp(float x) { return __builtin_amdgcn_rcpf(x); }

__global__ __launch_bounds__(BLK, 2)
void genlstm_kernel(const float* __restrict__ noise,
                    const float* __restrict__ eps,
                    const float* __restrict__ Wx,
                    const float* __restrict__ Wh,
                    const float* __restrict__ bgate,
                    const float* __restrict__ Wm1, const float* __restrict__ bm1,
                    const float* __restrict__ Wm2, const float* __restrict__ bm2,
                    const float* __restrict__ Wm3, const float* __restrict__ bm3,
                    const float* __restrict__ Wv1, const float* __restrict__ bv1,
                    const float* __restrict__ Wv2, const float* __restrict__ bv2,
                    const float* __restrict__ Wv3, const float* __restrict__ bv3,
                    float* __restrict__ out)
{
  // LDS. Layouts chosen so every access is either a wave-broadcast (same addr)
  // or lane-consecutive (<=2-way bank aliasing, free). 68-padding makes 8
  // distinct row-addresses land in distinct banks for the head/8-row reads.
  __shared__ __align__(16) float inb[R][96];     // [x(0:8) | noise(8:24) | h(24:88) | pad]
  __shared__ __align__(16) float zbuf[R][GATE];
  __shared__ __align__(16) float pm[4][R][HDI];
  __shared__ __align__(16) float pv[4][R][HDI];
  __shared__ __align__(16) float am1[R][68];
  __shared__ __align__(16) float av1[R][68];
  __shared__ __align__(16) float am2[R][68];
  __shared__ __align__(16) float av2[R][68];
  __shared__ __align__(16) float wm3t[SDI][68];  // transposed head weights
  __shared__ __align__(16) float wv3t[SDI][68];

  const int tid = threadIdx.x;
  const int w = tid >> 6;    // wave id 0..3
  const int n = tid & 63;
  const long rowbase = (long)blockIdx.x * R;

  // ---- one-time weight staging ----
  // gate column t of [Wx;Wh] in registers (static indexing only -> stays in VGPRs)
  float wcat[KCAT];
  #pragma unroll
  for (int k = 0; k < INDIM; ++k) wcat[k] = Wx[k * GATE + tid];
  #pragma unroll
  for (int k = 0; k < HDI; ++k) wcat[INDIM + k] = Wh[k * GATE + tid];
  const float bg = bgate[tid];

  // MLP weights: lane (w,n) owns k-slice [16w,16w+16) of column n of each matrix
  float wm1s[16], wm2s[16], wv1s[16], wv2s[16];
  #pragma unroll
  for (int kk = 0; kk < 16; ++kk) {
    wm1s[kk] = Wm1[(16 * w + kk) * HDI + n];
    wm2s[kk] = Wm2[(16 * w + kk) * HDI + n];
    wv1s[kk] = Wv1[(16 * w + kk) * HDI + n];
    wv2s[kk] = Wv2[(16 * w + kk) * HDI + n];
  }
  const float bm1r = bm1[n], bm2r = bm2[n], bv1r = bv1[n], bv2r = bv2[n];

  const int hr = tid >> 3;   // head row (threads 0..63)
  const int hd = tid & 7;    // head dim
  float bm3r = 0.f, bv3r = 0.f;
  if (tid < 64) { bm3r = bm3[hd]; bv3r = bv3[hd]; }

  for (int idx = tid; idx < HDI * SDI; idx += BLK) {
    int k = idx >> 3, d = idx & 7;
    wm3t[d][k] = Wm3[idx];
    wv3t[d][k] = Wv3[idx];
  }
  for (int idx = tid; idx < R * 96; idx += BLK) (&inb[0][0])[idx] = 0.f;

  float c0 = 0.f, c1 = 0.f, cum = 0.f;

  // out[:,0,:] = 0  (x0 = zeros, cumsum row 0)
  if (tid < 64) out[((rowbase + hr) * 256) * SDI + hd] = 0.f;

  __syncthreads();

  // noise for ts=0
  if (tid >= 128) {
    int idx = tid - 128;
    int r = idx >> 4, j = idx & 15;
    inb[r][8 + j] = noise[((rowbase + r) * TSTEPS) * NDI + j];
  }
  __syncthreads();

  for (int ts = 0; ts < TSTEPS; ++ts) {
    // ---- prefetch next-step noise & this-step eps (latency hides under compute)
    float nv = 0.f, ev = 0.f;
    if (tid >= 128 && ts + 1 < TSTEPS) {
      int idx = tid - 128;
      int r = idx >> 4, j = idx & 15;
      nv = noise[((rowbase + r) * TSTEPS + ts + 1) * NDI + j];
    }
    if (tid < 64) {
      ev = eps[((rowbase + hr) * TSTEPS + ts) * SDI + hd];
    }

    // ---- gates: z[r][tid] = b + dot88(in[r], wcat)  (input broadcast b128)
    for (int r = 0; r < R; ++r) {
      const float4* ip = (const float4*)(&inb[r][0]);
      float z0 = bg, z1 = 0.f, z2 = 0.f, z3 = 0.f;
      #pragma unroll
      for (int k4 = 0; k4 < 22; ++k4) {
        float4 v = ip[k4];
        z0 = fmaf(v.x, wcat[4 * k4 + 0], z0);
        z1 = fmaf(v.y, wcat[4 * k4 + 1], z1);
        z2 = fmaf(v.z, wcat[4 * k4 + 2], z2);
        z3 = fmaf(v.w, wcat[4 * k4 + 3], z3);
      }
      zbuf[r][tid] = (z0 + z1) + (z2 + z3);
    }
    __syncthreads();

    // ---- c/h update: thread (w,n) owns rows w and w+4, col n
    {
      const int r = w;
      float zi = zbuf[r][n], zf = zbuf[r][64 + n], zg = zbuf[r][128 + n], zo = zbuf[r][192 + n];
      float si = frcp(1.f + __expf(-zi));
      float sf = frcp(1.f + __expf(-zf));
      float so = frcp(1.f + __expf(-zo));
      float ag = fabsf(zg), eg = __expf(-2.f * ag);
      float tg = copysignf((1.f - eg) * frcp(1.f + eg), zg);
      c0 = fmaf(sf, c0, si * tg);
      float ac = fabsf(c0), ec = __expf(-2.f * ac);
      float tc = copysignf((1.f - ec) * frcp(1.f + ec), c0);
      inb[r][24 + n] = so * tc;
    }
    {
      const int r = w + 4;
      float zi = zbuf[r][n], zf = zbuf[r][64 + n], zg = zbuf[r][128 + n], zo = zbuf[r][192 + n];
      float si = frcp(1.f + __expf(-zi));
      float sf = frcp(1.f + __expf(-zf));
      float so = frcp(1.f + __expf(-zo));
      float ag = fabsf(zg), eg = __expf(-2.f * ag);
      float tg = copysignf((1.f - eg) * frcp(1.f + eg), zg);
      c1 = fmaf(sf, c1, si * tg);
      float ac = fabsf(c1), ec = __expf(-2.f * ac);
      float tc = copysignf((1.f - ec) * frcp(1.f + ec), c1);
      inb[r][24 + n] = so * tc;
    }
    __syncthreads();

    // ---- MLP layer 1: per-wave k-slice partials (both chains)
    for (int r = 0; r < R; ++r) {
      const float4* hp = (const float4*)(&inb[r][24 + 16 * w]);
      float pa = 0.f, pb = 0.f, qa = 0.f, qb = 0.f;
      #pragma unroll
      for (int kk = 0; kk < 4; ++kk) {
        float4 hv = hp[kk];
        pa = fmaf(hv.x, wm1s[4 * kk + 0], pa);
        pb = fmaf(hv.y, wm1s[4 * kk + 1], pb);
        pa = fmaf(hv.z, wm1s[4 * kk + 2], pa);
        pb = fmaf(hv.w, wm1s[4 * kk + 3], pb);
        qa = fmaf(hv.x, wv1s[4 * kk + 0], qa);
        qb = fmaf(hv.y, wv1s[4 * kk + 1], qb);
        qa = fmaf(hv.z, wv1s[4 * kk + 2], qa);
        qb = fmaf(hv.w, wv1s[4 * kk + 3], qb);
      }
      pm[w][r][n] = pa + pb;
      pv[w][r][n] = qa + qb;
    }
    __syncthreads();

    // ---- reduce 1 + bias + relu
    #pragma unroll
    for (int rr = 0; rr < 2; ++rr) {
      int r = w + rr * 4;
      float sm = ((pm[0][r][n] + pm[1][r][n]) + (pm[2][r][n] + pm[3][r][n])) + bm1r;
      float sv = ((pv[0][r][n] + pv[1][r][n]) + (pv[2][r][n] + pv[3][r][n])) + bv1r;
      am1[r][n] = fmaxf(sm, 0.f);
      av1[r][n] = fmaxf(sv, 0.f);
    }
    __syncthreads();

    // ---- MLP layer 2 partials
    for (int r = 0; r < R; ++r) {
      const float4* ap = (const float4*)(&am1[r][16 * w]);
      const float4* vp = (const float4*)(&av1[r][16 * w]);
      float pa = 0.f, pb = 0.f, qa = 0.f, qb = 0.f;
      #pragma unroll
      for (int kk = 0; kk < 4; ++kk) {
        float4 a = ap[kk];
        float4 vv = vp[kk];
        pa = fmaf(a.x, wm2s[4 * kk + 0], pa);
        pb = fmaf(a.y, wm2s[4 * kk + 1], pb);
        pa = fmaf(a.z, wm2s[4 * kk + 2], pa);
        pb = fmaf(a.w, wm2s[4 * kk + 3], pb);
        qa = fmaf(vv.x, wv2s[4 * kk + 0], qa);
        qb = fmaf(vv.y, wv2s[4 * kk + 1], qb);
        qa = fmaf(vv.z, wv2s[4 * kk + 2], qa);
        qb = fmaf(vv.w, wv2s[4 * kk + 3], qb);
      }
      pm[w][r][n] = pa + pb;
      pv[w][r][n] = qa + qb;
    }
    __syncthreads();

    // ---- reduce 2 + bias + relu
    #pragma unroll
    for (int rr = 0; rr < 2; ++rr) {
      int r = w + rr * 4;
      float sm = ((pm[0][r][n] + pm[1][r][n]) + (pm[2][r][n] + pm[3][r][n])) + bm2r;
      float sv = ((pv[0][r][n] + pv[1][r][n]) + (pv[2][r][n] + pv[3][r][n])) + bv2r;
      am2[r][n] = fmaxf(sm, 0.f);
      av2[r][n] = fmaxf(sv, 0.f);
    }
    __syncthreads();

    // ---- head (threads 0..63): mu, logvar, sample, cumsum, feedback x
    if (tid < 64) {
      const float4* ap = (const float4*)(&am2[hr][0]);
      const float4* vp = (const float4*)(&av2[hr][0]);
      const float4* wmp = (const float4*)(&wm3t[hd][0]);
      const float4* wvp = (const float4*)(&wv3t[hd][0]);
      float m0 = bm3r, m1 = 0.f, m2 = 0.f, m3 = 0.f;
      float l0 = bv3r, l1 = 0.f, l2 = 0.f, l3 = 0.f;
      #pragma unroll
      for (int k4 = 0; k4 < 16; ++k4) {
        float4 a = ap[k4], wm = wmp[k4];
        m0 = fmaf(a.x, wm.x, m0);
        m1 = fmaf(a.y, wm.y, m1);
        m2 = fmaf(a.z, wm.z, m2);
        m3 = fmaf(a.w, wm.w, m3);
        float4 av = vp[k4], wv = wvp[k4];
        l0 = fmaf(av.x, wv.x, l0);
        l1 = fmaf(av.y, wv.y, l1);
        l2 = fmaf(av.z, wv.z, l2);
        l3 = fmaf(av.w, wv.w, l3);
      }
      float mu = (m0 + m1) + (m2 + m3);
      float lv = (l0 + l1) + (l2 + l3);
      float sdv = __expf(0.5f * lv);
      float x = fmaf(sdv, ev, mu);
      cum += x;
      out[((rowbase + hr) * 256 + ts + 1) * SDI + hd] = cum;
      inb[hr][hd] = x;
    }
    // noise for next step into LDS (global load issued at step start)
    if (tid >= 128 && ts + 1 < TSTEPS) {
      int idx = tid - 128;
      int r = idx >> 4, j = idx & 15;
      inb[r][8 + j] = nv;
    }
    __syncthreads();
  }
}

extern "C" void kernel_launch(void* const* d_in, const int* in_sizes, int n_in,
                              void* d_out, int out_size, void* d_ws, size_t ws_size,
                              hipStream_t stream) {
  const float* noise = (const float*)d_in[0];
  const float* eps   = (const float*)d_in[1];
  const float* Wx    = (const float*)d_in[2];
  const float* Wh    = (const float*)d_in[3];
  const float* bg    = (const float*)d_in[4];
  const float* Wm1   = (const float*)d_in[5];
  const float* bm1   = (const float*)d_in[6];
  const float* Wm2   = (const float*)d_in[7];
  const float* bm2   = (const float*)d_in[8];
  const float* Wm3   = (const float*)d_in[9];
  const float* bm3   = (const float*)d_in[10];
  const float* Wv1   = (const float*)d_in[11];
  const float* bv1   = (const float*)d_in[12];
  const float* Wv2   = (const float*)d_in[13];
  const float* bv2   = (const float*)d_in[14];
  const float* Wv3   = (const float*)d_in[15];
  const float* bv3   = (const float*)d_in[16];
  float* out = (float*)d_out;

  dim3 grid(4096 / R), block(BLK);
  hipLaunchKernelGGL(genlstm_kernel, grid, block, 0, stream,
                     noise, eps, Wx, Wh, bg, Wm1, bm1, Wm2, bm2, Wm3, bm3,
                     Wv1, bv1, Wv2, bv2, Wv3, bv3, out);
}

// Round 4
// 663.712 us; speedup vs baseline: 3.5370x; 3.5370x over previous
//
#include <hip/hip_runtime.h>

typedef _Float16 half8 __attribute__((ext_vector_type(8)));
typedef float f32x4 __attribute__((ext_vector_type(4)));

#define TSTEPS 255
#define R 16
#define BLK 512
#define XS 100   // xin stride: [x(0:8)|noise(8:24)|h(24:88)|zero-pad(88:96)|pad]
#define ZS 260   // z2 stride (16 rows x 256 gate cols)
#define AS 68    // a1/a2 stride

__device__ __forceinline__ float frcp(float x) { return __builtin_amdgcn_rcpf(x); }

__device__ __forceinline__ f32x4 mfma16(half8 a, half8 b, f32x4 c) {
  return __builtin_amdgcn_mfma_f32_16x16x32_f16(a, b, c, 0, 0, 0);
}

// load 8 consecutive fp32 from LDS, split into hi/lo f16 (3-term emulation)
__device__ __forceinline__ void ldcvt8(const float* p, half8& hi, half8& lo) {
  const float4 u = *(const float4*)p;
  const float4 v = *(const float4*)(p + 4);
  const float a[8] = {u.x, u.y, u.z, u.w, v.x, v.y, v.z, v.w};
  #pragma unroll
  for (int j = 0; j < 8; ++j) {
    _Float16 h = (_Float16)a[j];
    hi[j] = h;
    lo[j] = (_Float16)(a[j] - (float)h);
  }
}

__global__ __launch_bounds__(BLK)
void genlstm_kernel(const float* __restrict__ noise,
                    const float* __restrict__ eps,
                    const float* __restrict__ Wx,
                    const float* __restrict__ Wh,
                    const float* __restrict__ bg,
                    const float* __restrict__ Wm1, const float* __restrict__ bm1,
                    const float* __restrict__ Wm2, const float* __restrict__ bm2,
                    const float* __restrict__ Wm3, const float* __restrict__ bm3,
                    const float* __restrict__ Wv1, const float* __restrict__ bv1,
                    const float* __restrict__ Wv2, const float* __restrict__ bv2,
                    const float* __restrict__ Wv3, const float* __restrict__ bv3,
                    float* __restrict__ out)
{
  __shared__ __align__(16) float xin[R][XS];
  __shared__ __align__(16) float z2[R][ZS];
  __shared__ __align__(16) float a1[2][R][AS];
  __shared__ __align__(16) float a2[2][R][AS];
  __shared__ __align__(16) float mulv[2][R][9];

  const int tid  = threadIdx.x;
  const int w    = tid >> 6;       // wave 0..7
  const int l    = tid & 63;
  const int lrow = l & 15;         // A-row / B-col / C-col within a 16x16 tile
  const int lq   = l >> 4;         // k-group (8 elems each)
  const long rowbase = (long)blockIdx.x * R;

  // ---------------- one-time weight fragment staging (registers) ----------------
  // Gate B: wave w owns gate cols 32w..32w+31 (2 N-tiles), K = 96 (88 + zero pad)
  half8 gBhi[2][3], gBlo[2][3];
  #pragma unroll
  for (int t = 0; t < 2; ++t)
    #pragma unroll
    for (int kt = 0; kt < 3; ++kt)
      #pragma unroll
      for (int j = 0; j < 8; ++j) {
        int k = 32 * kt + 8 * lq + j;
        int n = 32 * w + 16 * t + lrow;
        float v = 0.f;
        if (k < 24) v = Wx[k * 256 + n];
        else if (k < 88) v = Wh[(k - 24) * 256 + n];
        _Float16 h = (_Float16)v;
        gBhi[t][kt][j] = h;
        gBlo[t][kt][j] = (_Float16)(v - (float)h);
      }

  // MLP tiles: wave w -> chain = w>>2 (0:mu, 1:var), N-tile nt = w&3
  const int chain = w >> 2;
  const int nt = w & 3;
  const float* W1 = chain ? Wv1 : Wm1;
  const float* W2 = chain ? Wv2 : Wm2;
  half8 B1hi[2], B1lo[2], B2hi[2], B2lo[2];
  #pragma unroll
  for (int kt = 0; kt < 2; ++kt)
    #pragma unroll
    for (int j = 0; j < 8; ++j) {
      int k = 32 * kt + 8 * lq + j;
      int n = 16 * nt + lrow;
      float v1 = W1[k * 64 + n];
      _Float16 h1 = (_Float16)v1;
      B1hi[kt][j] = h1; B1lo[kt][j] = (_Float16)(v1 - (float)h1);
      float v2 = W2[k * 64 + n];
      _Float16 h2 = (_Float16)v2;
      B2hi[kt][j] = h2; B2lo[kt][j] = (_Float16)(v2 - (float)h2);
    }

  // Head: wave 0 -> Wm3 (mu), wave 1 -> Wv3 (logvar); cols 8..15 zero-padded
  half8 B3hi[2], B3lo[2];
  if (w < 2) {
    const float* W3 = w ? Wv3 : Wm3;
    #pragma unroll
    for (int kt = 0; kt < 2; ++kt)
      #pragma unroll
      for (int j = 0; j < 8; ++j) {
        int k = 32 * kt + 8 * lq + j;
        float v = (lrow < 8) ? W3[k * 8 + lrow] : 0.f;
        _Float16 h = (_Float16)v;
        B3hi[kt][j] = h;
        B3lo[kt][j] = (_Float16)(v - (float)h);
      }
  }

  // biases
  const float bias1 = (chain ? bv1 : bm1)[16 * nt + lrow];
  const float bias2 = (chain ? bv2 : bm2)[16 * nt + lrow];
  float bias3 = 0.f;
  if (w < 2 && lrow < 8) bias3 = (w ? bv3 : bm3)[lrow];

  // gate biases for the nonlinearity stage (thread owns col l, rows w & w+8)
  const float bgi = bg[l], bgf = bg[64 + l], bgg = bg[128 + l], bgo = bg[192 + l];

  float cst0 = 0.f, cst1 = 0.f;   // c-state rows w and w+8, col l
  const int r5 = tid >> 3, d5 = tid & 7;  // head/sample mapping (threads < 128)
  float cum = 0.f;

  // ---------------- prologue ----------------
  for (int i = tid; i < R * XS; i += BLK) (&xin[0][0])[i] = 0.f;
  if (tid < 128) out[((rowbase + r5) * 256) * 8 + d5] = 0.f;  // cumsum row 0 = x0 = 0
  __syncthreads();

  float4 nz = {0.f, 0.f, 0.f, 0.f};
  if (tid < 64) {
    int r = tid >> 2, j4 = (tid & 3) * 4;
    *(float4*)&xin[r][8 + j4] =
        *(const float4*)&noise[((rowbase + r) * TSTEPS) * 16 + j4];       // noise[0]
    nz = *(const float4*)&noise[((rowbase + r) * TSTEPS + 1) * 16 + j4];  // noise[1]
  }
  float ev = 0.f;
  if (tid < 128) ev = eps[((rowbase + r5) * TSTEPS) * 8 + d5];            // eps[0]
  __syncthreads();

  // ---------------- time loop ----------------
  for (int ts = 0; ts < TSTEPS; ++ts) {
    // S0: gate A fragments (all waves, same data) + 18 MFMA + z2 store
    half8 Ahi[3], Alo[3];
    #pragma unroll
    for (int kt = 0; kt < 3; ++kt)
      ldcvt8(&xin[lrow][32 * kt + 8 * lq], Ahi[kt], Alo[kt]);

    f32x4 accz0 = {0.f, 0.f, 0.f, 0.f};
    f32x4 accz1 = {0.f, 0.f, 0.f, 0.f};
    #pragma unroll
    for (int kt = 0; kt < 3; ++kt) {
      accz0 = mfma16(Ahi[kt], gBhi[0][kt], accz0);
      accz1 = mfma16(Ahi[kt], gBhi[1][kt], accz1);
      accz0 = mfma16(Alo[kt], gBhi[0][kt], accz0);
      accz1 = mfma16(Alo[kt], gBhi[1][kt], accz1);
      accz0 = mfma16(Ahi[kt], gBlo[0][kt], accz0);
      accz1 = mfma16(Ahi[kt], gBlo[1][kt], accz1);
    }
    {
      const int r0 = 4 * lq;
      #pragma unroll
      for (int k = 0; k < 4; ++k) {
        z2[r0 + k][32 * w + lrow]      = accz0[k];
        z2[r0 + k][32 * w + 16 + lrow] = accz1[k];
      }
    }
    __syncthreads();  // A: xin fully consumed, z2 complete

    // S1: gate nonlinearity + c/h update (2 rows per thread) + noise feed
    #pragma unroll
    for (int rr = 0; rr < 2; ++rr) {
      const int r = w + rr * 8;
      float zi = z2[r][l]       + bgi;
      float zf = z2[r][64 + l]  + bgf;
      float zg = z2[r][128 + l] + bgg;
      float zo = z2[r][192 + l] + bgo;
      float si = frcp(1.f + __expf(-zi));
      float sf = frcp(1.f + __expf(-zf));
      float so = frcp(1.f + __expf(-zo));
      float ag = fabsf(zg), eg = __expf(-2.f * ag);
      float tg = copysignf((1.f - eg) * frcp(1.f + eg), zg);
      float cs = rr ? cst1 : cst0;
      cs = fmaf(sf, cs, si * tg);
      if (rr) cst1 = cs; else cst0 = cs;
      float ac = fabsf(cs), ec = __expf(-2.f * ac);
      float tc = copysignf((1.f - ec) * frcp(1.f + ec), cs);
      xin[r][24 + l] = so * tc;
    }
    if (tid < 64) {
      int r = tid >> 2, j4 = (tid & 3) * 4;
      *(float4*)&xin[r][8 + j4] = nz;  // noise[ts+1]
      if (ts + 2 < TSTEPS)
        nz = *(const float4*)&noise[((rowbase + r) * TSTEPS + ts + 2) * 16 + j4];
    }
    __syncthreads();  // B: h (and next noise) in xin

    // S2: MLP layer 1
    {
      half8 hhi[2], hlo[2];
      #pragma unroll
      for (int kt = 0; kt < 2; ++kt)
        ldcvt8(&xin[lrow][24 + 32 * kt + 8 * lq], hhi[kt], hlo[kt]);
      f32x4 acc = {0.f, 0.f, 0.f, 0.f};
      #pragma unroll
      for (int kt = 0; kt < 2; ++kt) {
        acc = mfma16(hhi[kt], B1hi[kt], acc);
        acc = mfma16(hlo[kt], B1hi[kt], acc);
        acc = mfma16(hhi[kt], B1lo[kt], acc);
      }
      const int r0 = 4 * lq;
      #pragma unroll
      for (int k = 0; k < 4; ++k)
        a1[chain][r0 + k][16 * nt + lrow] = fmaxf(acc[k] + bias1, 0.f);
    }
    __syncthreads();  // C

    // S3: MLP layer 2
    {
      half8 ahi[2], alo[2];
      #pragma unroll
      for (int kt = 0; kt < 2; ++kt)
        ldcvt8(&a1[chain][lrow][32 * kt + 8 * lq], ahi[kt], alo[kt]);
      f32x4 acc = {0.f, 0.f, 0.f, 0.f};
      #pragma unroll
      for (int kt = 0; kt < 2; ++kt) {
        acc = mfma16(ahi[kt], B2hi[kt], acc);
        acc = mfma16(alo[kt], B2hi[kt], acc);
        acc = mfma16(ahi[kt], B2lo[kt], acc);
      }
      const int r0 = 4 * lq;
      #pragma unroll
      for (int k = 0; k < 4; ++k)
        a2[chain][r0 + k][16 * nt + lrow] = fmaxf(acc[k] + bias2, 0.f);
    }
    __syncthreads();  // D

    // S4: heads (wave 0: mu, wave 1: logvar)
    if (w < 2) {
      half8 chi[2], clo[2];
      #pragma unroll
      for (int kt = 0; kt < 2; ++kt)
        ldcvt8(&a2[w][lrow][32 * kt + 8 * lq], chi[kt], clo[kt]);
      f32x4 acc = {0.f, 0.f, 0.f, 0.f};
      #pragma unroll
      for (int kt = 0; kt < 2; ++kt) {
        acc = mfma16(chi[kt], B3hi[kt], acc);
        acc = mfma16(clo[kt], B3hi[kt], acc);
        acc = mfma16(chi[kt], B3lo[kt], acc);
      }
      if (lrow < 8) {
        const int r0 = 4 * lq;
        #pragma unroll
        for (int k = 0; k < 4; ++k)
          mulv[w][r0 + k][lrow] = acc[k] + bias3;
      }
    }
    __syncthreads();  // E

    // S5: sample, cumsum, output, x feedback (threads < 128)
    if (tid < 128) {
      float mu = mulv[0][r5][d5];
      float lv = mulv[1][r5][d5];
      float x = fmaf(__expf(0.5f * lv), ev, mu);
      cum += x;
      out[((rowbase + r5) * 256 + ts + 1) * 8 + d5] = cum;
      xin[r5][d5] = x;
      if (ts + 1 < TSTEPS)
        ev = eps[((rowbase + r5) * TSTEPS + ts + 1) * 8 + d5];
    }
    __syncthreads();  // F: x in xin, safe for next S0
  }
}

extern "C" void kernel_launch(void* const* d_in, const int* in_sizes, int n_in,
                              void* d_out, int out_size, void* d_ws, size_t ws_size,
                              hipStream_t stream) {
  const float* noise = (const float*)d_in[0];
  const float* eps   = (const float*)d_in[1];
  const float* Wx    = (const float*)d_in[2];
  const float* Wh    = (const float*)d_in[3];
  const float* bg    = (const float*)d_in[4];
  const float* Wm1   = (const float*)d_in[5];
  const float* bm1   = (const float*)d_in[6];
  const float* Wm2   = (const float*)d_in[7];
  const float* bm2   = (const float*)d_in[8];
  const float* Wm3   = (const float*)d_in[9];
  const float* bm3   = (const float*)d_in[10];
  const float* Wv1   = (const float*)d_in[11];
  const float* bv1   = (const float*)d_in[12];
  const float* Wv2   = (const float*)d_in[13];
  const float* bv2   = (const float*)d_in[14];
  const float* Wv3   = (const float*)d_in[15];
  const float* bv3   = (const float*)d_in[16];
  float* out = (float*)d_out;

  dim3 grid(4096 / R), block(BLK);
  hipLaunchKernelGGL(genlstm_kernel, grid, block, 0, stream,
                     noise, eps, Wx, Wh, bg, Wm1, bm1, Wm2, bm2, Wm3, bm3,
                     Wv1, bv1, Wv2, bv2, Wv3, bv3, out);
}

// Round 5
// 589.144 us; speedup vs baseline: 3.9847x; 1.1266x over previous
//
#include <hip/hip_runtime.h>

typedef _Float16 half8 __attribute__((ext_vector_type(8)));
typedef _Float16 half4 __attribute__((ext_vector_type(4)));
typedef float f32x4 __attribute__((ext_vector_type(4)));

#define TSTEPS 255
#define R 16
#define BLK 512
#define XSH 104   // xh/xl stride (halves): [h(0:64)|x(64:72)|noise(72:88)|zero(88:96)|pad]
#define ZS 260    // z2 stride (f32), interleaved cols: z'[4*hc+g] = gate g of h-col hc
#define ASH 72    // a-plane stride (halves)

__device__ __forceinline__ float frcp(float x) { return __builtin_amdgcn_rcpf(x); }

__device__ __forceinline__ f32x4 mfma16(half8 a, half8 b, f32x4 c) {
  return __builtin_amdgcn_mfma_f32_16x16x32_f16(a, b, c, 0, 0, 0);
}

__global__ __launch_bounds__(BLK)
void genlstm_kernel(const float* __restrict__ noise,
                    const float* __restrict__ eps,
                    const float* __restrict__ Wx,
                    const float* __restrict__ Wh,
                    const float* __restrict__ bg,
                    const float* __restrict__ Wm1, const float* __restrict__ bm1,
                    const float* __restrict__ Wm2, const float* __restrict__ bm2,
                    const float* __restrict__ Wm3, const float* __restrict__ bm3,
                    const float* __restrict__ Wv1, const float* __restrict__ bv1,
                    const float* __restrict__ Wv2, const float* __restrict__ bv2,
                    const float* __restrict__ Wv3, const float* __restrict__ bv3,
                    float* __restrict__ out)
{
  __shared__ __align__(16) _Float16 xh[R][XSH];
  __shared__ __align__(16) _Float16 xl[R][XSH];
  __shared__ __align__(16) float    z2[R][ZS];
  __shared__ __align__(16) _Float16 a1h[2][R][ASH];
  __shared__ __align__(16) _Float16 a1l[2][R][ASH];
  __shared__ __align__(16) _Float16 a2h[2][R][ASH];
  __shared__ __align__(16) _Float16 a2l[2][R][ASH];
  __shared__ __align__(16) float    mulv[2][R][12];

  const int tid  = threadIdx.x;
  const int w    = tid >> 6;   // wave 0..7
  const int l    = tid & 63;
  const int lrow = l & 15;     // tile row/col within 16x16
  const int lq   = l >> 4;     // k-group (8 elems)
  const long rowbase = (long)blockIdx.x * R;

  // ---------- one-time weight fragment staging ----------
  // Gate B: staged col jc -> original gate col 64*(jc&3) + (jc>>2)  (z' interleave);
  // k reordered: [Wh rows 0..63 | Wx rows 0..23 | zeros]
  half8 gBhi[2][3], gBlo[2][3];
  #pragma unroll
  for (int t = 0; t < 2; ++t)
    #pragma unroll
    for (int kt = 0; kt < 3; ++kt)
      #pragma unroll
      for (int j = 0; j < 8; ++j) {
        int k  = 32 * kt + 8 * lq + j;
        int jc = 32 * w + 16 * t + lrow;
        int n  = 64 * (jc & 3) + (jc >> 2);
        float v = 0.f;
        if (k < 64) v = Wh[k * 256 + n];
        else if (k < 88) v = Wx[(k - 64) * 256 + n];
        _Float16 h = (_Float16)v;
        gBhi[t][kt][j] = h;
        gBlo[t][kt][j] = (_Float16)(v - (float)h);
      }

  // MLP tiles: chain = w>>2 (0:mu 1:var), N-tile nt = w&3
  const int chain = w >> 2;
  const int nt = w & 3;
  const float* W1 = chain ? Wv1 : Wm1;
  const float* W2 = chain ? Wv2 : Wm2;
  half8 B1hi[2], B1lo[2], B2hi[2], B2lo[2];
  #pragma unroll
  for (int kt = 0; kt < 2; ++kt)
    #pragma unroll
    for (int j = 0; j < 8; ++j) {
      int k = 32 * kt + 8 * lq + j;
      int n = 16 * nt + lrow;
      float v1 = W1[k * 64 + n];
      _Float16 h1 = (_Float16)v1;
      B1hi[kt][j] = h1; B1lo[kt][j] = (_Float16)(v1 - (float)h1);
      float v2 = W2[k * 64 + n];
      _Float16 h2 = (_Float16)v2;
      B2hi[kt][j] = h2; B2lo[kt][j] = (_Float16)(v2 - (float)h2);
    }

  // Heads: wave 0 mu, wave 1 logvar
  half8 B3hi[2], B3lo[2];
  if (w < 2) {
    const float* W3 = w ? Wv3 : Wm3;
    #pragma unroll
    for (int kt = 0; kt < 2; ++kt)
      #pragma unroll
      for (int j = 0; j < 8; ++j) {
        int k = 32 * kt + 8 * lq + j;
        float v = (lrow < 8) ? W3[k * 8 + lrow] : 0.f;
        _Float16 h = (_Float16)v;
        B3hi[kt][j] = h;
        B3lo[kt][j] = (_Float16)(v - (float)h);
      }
  }

  const float bias1 = (chain ? bv1 : bm1)[16 * nt + lrow];
  const float bias2 = (chain ? bv2 : bm2)[16 * nt + lrow];
  float bias3 = 0.f;
  if (w < 2 && lrow < 8) bias3 = (w ? bv3 : bm3)[lrow];

  // gate biases as float4 matching z' float4 read: {i,f,g,o} of h-col l
  const float4 bgq = {bg[l], bg[64 + l], bg[128 + l], bg[192 + l]};

  float cst0 = 0.f, cst1 = 0.f;            // c-state rows w, w+8, col l
  const int r5 = tid >> 3, d5 = tid & 7;   // sampler mapping (threads < 128)
  float cum = 0.f;

  // persistent h fragments (h0 = 0); reloaded each step in S2, reused in next S0
  half8 hHi[2], hLo[2];
  #pragma unroll
  for (int kt = 0; kt < 2; ++kt)
    #pragma unroll
    for (int j = 0; j < 8; ++j) { hHi[kt][j] = (_Float16)0; hLo[kt][j] = (_Float16)0; }

  // ---------- prologue ----------
  for (int i = tid; i < R * XSH; i += BLK) {
    (&xh[0][0])[i] = (_Float16)0;
    (&xl[0][0])[i] = (_Float16)0;
  }
  if (tid < 128) out[((rowbase + r5) * 256) * 8 + d5] = 0.f;  // cumsum row 0
  __syncthreads();

  float4 nz = {0.f, 0.f, 0.f, 0.f};
  if (tid < 64) {
    int r = tid >> 2, j4 = (tid & 3) * 4;
    float4 n0 = *(const float4*)&noise[((rowbase + r) * TSTEPS) * 16 + j4];
    float tmp[4] = {n0.x, n0.y, n0.z, n0.w};
    half4 nh, nl;
    #pragma unroll
    for (int j = 0; j < 4; ++j) {
      _Float16 h = (_Float16)tmp[j];
      nh[j] = h; nl[j] = (_Float16)(tmp[j] - (float)h);
    }
    *(half4*)&xh[r][72 + j4] = nh;
    *(half4*)&xl[r][72 + j4] = nl;
    nz = *(const float4*)&noise[((rowbase + r) * TSTEPS + 1) * 16 + j4];
  }
  float ev = 0.f;
  if (tid < 128) ev = eps[((rowbase + r5) * TSTEPS) * 8 + d5];
  __syncthreads();

  // ---------- time loop ----------
  for (int ts = 0; ts < TSTEPS; ++ts) {
    // S0: gate MFMA. h-frags (kt 0,1) from registers; x|noise frag fresh.
    half8 Xhi = *(const half8*)&xh[lrow][64 + 8 * lq];
    half8 Xlo = *(const half8*)&xl[lrow][64 + 8 * lq];

    f32x4 accz0 = {0.f, 0.f, 0.f, 0.f};
    f32x4 accz1 = {0.f, 0.f, 0.f, 0.f};
    accz0 = mfma16(hHi[0], gBhi[0][0], accz0);
    accz1 = mfma16(hHi[0], gBhi[1][0], accz1);
    accz0 = mfma16(hLo[0], gBhi[0][0], accz0);
    accz1 = mfma16(hLo[0], gBhi[1][0], accz1);
    accz0 = mfma16(hHi[0], gBlo[0][0], accz0);
    accz1 = mfma16(hHi[0], gBlo[1][0], accz1);
    accz0 = mfma16(hHi[1], gBhi[0][1], accz0);
    accz1 = mfma16(hHi[1], gBhi[1][1], accz1);
    accz0 = mfma16(hLo[1], gBhi[0][1], accz0);
    accz1 = mfma16(hLo[1], gBhi[1][1], accz1);
    accz0 = mfma16(hHi[1], gBlo[0][1], accz0);
    accz1 = mfma16(hHi[1], gBlo[1][1], accz1);
    accz0 = mfma16(Xhi, gBhi[0][2], accz0);
    accz1 = mfma16(Xhi, gBhi[1][2], accz1);
    accz0 = mfma16(Xlo, gBhi[0][2], accz0);
    accz1 = mfma16(Xlo, gBhi[1][2], accz1);
    accz0 = mfma16(Xhi, gBlo[0][2], accz0);
    accz1 = mfma16(Xhi, gBlo[1][2], accz1);
    {
      const int r0 = 4 * lq;
      #pragma unroll
      for (int k = 0; k < 4; ++k) {
        z2[r0 + k][32 * w + lrow]      = accz0[k];
        z2[r0 + k][32 * w + 16 + lrow] = accz1[k];
      }
    }
    __syncthreads();  // A: z' complete

    // S1: gates -> c,h (rows w, w+8; h-col l); one float4 read per row
    #pragma unroll
    for (int rr = 0; rr < 2; ++rr) {
      const int r = w + rr * 8;
      float4 zq = *(const float4*)&z2[r][4 * l];
      float zi = zq.x + bgq.x;
      float zf = zq.y + bgq.y;
      float zg = zq.z + bgq.z;
      float zo = zq.w + bgq.w;
      float si = frcp(1.f + __expf(-zi));
      float sf = frcp(1.f + __expf(-zf));
      float so = frcp(1.f + __expf(-zo));
      float ag = fabsf(zg), eg = __expf(-2.f * ag);
      float tg = copysignf((1.f - eg) * frcp(1.f + eg), zg);
      float cs = rr ? cst1 : cst0;
      cs = fmaf(sf, cs, si * tg);
      if (rr) cst1 = cs; else cst0 = cs;
      float ac = fabsf(cs), ec = __expf(-2.f * ac);
      float tc = copysignf((1.f - ec) * frcp(1.f + ec), cs);
      float hv = so * tc;
      _Float16 hh = (_Float16)hv;
      xh[r][l] = hh;
      xl[r][l] = (_Float16)(hv - (float)hh);
    }
    if (tid < 64) {   // noise[ts+1] into planes; prefetch noise[ts+2]
      int r = tid >> 2, j4 = (tid & 3) * 4;
      float tmp[4] = {nz.x, nz.y, nz.z, nz.w};
      half4 nh, nl;
      #pragma unroll
      for (int j = 0; j < 4; ++j) {
        _Float16 h = (_Float16)tmp[j];
        nh[j] = h; nl[j] = (_Float16)(tmp[j] - (float)h);
      }
      *(half4*)&xh[r][72 + j4] = nh;
      *(half4*)&xl[r][72 + j4] = nl;
      if (ts + 2 < TSTEPS)
        nz = *(const float4*)&noise[((rowbase + r) * TSTEPS + ts + 2) * 16 + j4];
    }
    __syncthreads();  // B: h, next noise in planes

    // S2: MLP layer 1 (loads h frags -> kept for next S0)
    {
      hHi[0] = *(const half8*)&xh[lrow][8 * lq];
      hHi[1] = *(const half8*)&xh[lrow][32 + 8 * lq];
      hLo[0] = *(const half8*)&xl[lrow][8 * lq];
      hLo[1] = *(const half8*)&xl[lrow][32 + 8 * lq];
      f32x4 acc = {0.f, 0.f, 0.f, 0.f};
      #pragma unroll
      for (int kt = 0; kt < 2; ++kt) {
        acc = mfma16(hHi[kt], B1hi[kt], acc);
        acc = mfma16(hLo[kt], B1hi[kt], acc);
        acc = mfma16(hHi[kt], B1lo[kt], acc);
      }
      const int r0 = 4 * lq;
      #pragma unroll
      for (int k = 0; k < 4; ++k) {
        float v = fmaxf(acc[k] + bias1, 0.f);
        _Float16 vh = (_Float16)v;
        a1h[chain][r0 + k][16 * nt + lrow] = vh;
        a1l[chain][r0 + k][16 * nt + lrow] = (_Float16)(v - (float)vh);
      }
    }
    __syncthreads();  // C

    // S3: MLP layer 2
    {
      half8 ahi0 = *(const half8*)&a1h[chain][lrow][8 * lq];
      half8 ahi1 = *(const half8*)&a1h[chain][lrow][32 + 8 * lq];
      half8 alo0 = *(const half8*)&a1l[chain][lrow][8 * lq];
      half8 alo1 = *(const half8*)&a1l[chain][lrow][32 + 8 * lq];
      f32x4 acc = {0.f, 0.f, 0.f, 0.f};
      acc = mfma16(ahi0, B2hi[0], acc);
      acc = mfma16(alo0, B2hi[0], acc);
      acc = mfma16(ahi0, B2lo[0], acc);
      acc = mfma16(ahi1, B2hi[1], acc);
      acc = mfma16(alo1, B2hi[1], acc);
      acc = mfma16(ahi1, B2lo[1], acc);
      const int r0 = 4 * lq;
      #pragma unroll
      for (int k = 0; k < 4; ++k) {
        float v = fmaxf(acc[k] + bias2, 0.f);
        _Float16 vh = (_Float16)v;
        a2h[chain][r0 + k][16 * nt + lrow] = vh;
        a2l[chain][r0 + k][16 * nt + lrow] = (_Float16)(v - (float)vh);
      }
    }
    __syncthreads();  // D

    // S4: heads (wave 0: mu, wave 1: logvar)
    if (w < 2) {
      half8 chi0 = *(const half8*)&a2h[w][lrow][8 * lq];
      half8 chi1 = *(const half8*)&a2h[w][lrow][32 + 8 * lq];
      half8 clo0 = *(const half8*)&a2l[w][lrow][8 * lq];
      half8 clo1 = *(const half8*)&a2l[w][lrow][32 + 8 * lq];
      f32x4 acc = {0.f, 0.f, 0.f, 0.f};
      acc = mfma16(chi0, B3hi[0], acc);
      acc = mfma16(clo0, B3hi[0], acc);
      acc = mfma16(chi0, B3lo[0], acc);
      acc = mfma16(chi1, B3hi[1], acc);
      acc = mfma16(clo1, B3hi[1], acc);
      acc = mfma16(chi1, B3lo[1], acc);
      if (lrow < 8) {
        const int r0 = 4 * lq;
        #pragma unroll
        for (int k = 0; k < 4; ++k)
          mulv[w][r0 + k][lrow] = acc[k] + bias3;
      }
    }
    __syncthreads();  // E

    // S5: sample, cumsum, output, x feedback (threads < 128)
    if (tid < 128) {
      float mu = mulv[0][r5][d5];
      float lv = mulv[1][r5][d5];
      float x = fmaf(__expf(0.5f * lv), ev, mu);
      cum += x;
      out[((rowbase + r5) * 256 + ts + 1) * 8 + d5] = cum;
      _Float16 xhh = (_Float16)x;
      xh[r5][64 + d5] = xhh;
      xl[r5][64 + d5] = (_Float16)(x - (float)xhh);
      if (ts + 1 < TSTEPS)
        ev = eps[((rowbase + r5) * TSTEPS + ts + 1) * 8 + d5];
    }
    __syncthreads();  // F
  }
}

extern "C" void kernel_launch(void* const* d_in, const int* in_sizes, int n_in,
                              void* d_out, int out_size, void* d_ws, size_t ws_size,
                              hipStream_t stream) {
  const float* noise = (const float*)d_in[0];
  const float* eps   = (const float*)d_in[1];
  const float* Wx    = (const float*)d_in[2];
  const float* Wh    = (const float*)d_in[3];
  const float* bg    = (const float*)d_in[4];
  const float* Wm1   = (const float*)d_in[5];
  const float* bm1   = (const float*)d_in[6];
  const float* Wm2   = (const float*)d_in[7];
  const float* bm2   = (const float*)d_in[8];
  const float* Wm3   = (const float*)d_in[9];
  const float* bm3   = (const float*)d_in[10];
  const float* Wv1   = (const float*)d_in[11];
  const float* bv1   = (const float*)d_in[12];
  const float* Wv2   = (const float*)d_in[13];
  const float* bv2   = (const float*)d_in[14];
  const float* Wv3   = (const float*)d_in[15];
  const float* bv3   = (const float*)d_in[16];
  float* out = (float*)d_out;

  dim3 grid(4096 / R), block(BLK);
  hipLaunchKernelGGL(genlstm_kernel, grid, block, 0, stream,
                     noise, eps, Wx, Wh, bg, Wm1, bm1, Wm2, bm2, Wm3, bm3,
                     Wv1, bv1, Wv2, bv2, Wv3, bv3, out);
}